// Round 15
// baseline (226.669 us; speedup 1.0000x reference)
//
#include <hip/hip_runtime.h>

typedef __attribute__((ext_vector_type(8)))  _Float16 f16x8;
typedef __attribute__((ext_vector_type(2)))  __fp16   fp16x2;  // cvt_pkrtz return type
typedef __attribute__((ext_vector_type(4)))  float    f32x4;

#define TT 16384
#define KD 1024
#define ND 3072
#define NE 16
#define ASZ (TT * KD)                   // 16777216 elements
#define WSZ (NE * ND * KD)              // 50331648 elements
#define NEED_WS ((size_t)(ASZ + WSZ) * 2)

#define BM 256
#define BN 256
#define BK 64
#define NSTEP (KD / BK)                 // 16
#define ROWB (BK * 2)                   // 128 B per LDS row (f16)
#define NGEN 3                          // 768 tiles = 3 generations x 256 blocks

#define BAR() __builtin_amdgcn_s_barrier()
#define WAIT_VM(n) asm volatile("s_waitcnt vmcnt(" #n ")" ::: "memory")

// XOR swizzle: conflict-free ds_read_b128 column access on 128B rows (m201).
__device__ __forceinline__ int swz(int row, int kbyte) {
    return row * ROWB + (kbyte ^ ((row & 7) << 4));
}

__device__ __forceinline__ int find_expert(const void* cntp, int row0) {
    // JAX default config demotes int64 -> int32; detect which layout we got.
    const int* w = (const int*)cntp;
    int oddsum = 0;
    #pragma unroll
    for (int i = 1; i < 16; i += 2) oddsum |= w[i];
    int e = 0;
    long long cum = 0;
    if (oddsum == 0) {  // int64 counts
        const long long* c = (const long long*)cntp;
        #pragma unroll
        for (int i = 0; i < NE; ++i) { if ((long long)row0 >= cum) e = i; cum += c[i]; }
    } else {            // int32 counts
        #pragma unroll
        for (int i = 0; i < NE; ++i) { if ((long long)row0 >= cum) e = i; cum += w[i]; }
    }
    return e;
}

// Direct global->LDS DMA, 16B/lane. LDS dest = wave-uniform base + lane*16.
__device__ __forceinline__ void gl16(const void* g, void* l) {
    __builtin_amdgcn_global_load_lds(
        (const __attribute__((address_space(1))) unsigned int*)g,
        (__attribute__((address_space(3))) unsigned int*)l, 16, 0, 0);
}

// ---------------- pre-pass: fp32 -> f16 for A and W ----------------
__global__ __launch_bounds__(256) void cvt_kernel(const float* __restrict__ A,
                                                  const float* __restrict__ W,
                                                  _Float16* __restrict__ dst) {
    size_t i = ((size_t)blockIdx.x * 256 + threadIdx.x) * 8;
    const float* src = (i < (size_t)ASZ) ? (A + i) : (W + (i - ASZ));
    f32x4 v0 = *(const f32x4*)src;
    f32x4 v1 = *(const f32x4*)(src + 4);
    f16x8 h;
    h[0] = (_Float16)v0[0]; h[1] = (_Float16)v0[1];
    h[2] = (_Float16)v0[2]; h[3] = (_Float16)v0[3];
    h[4] = (_Float16)v1[0]; h[5] = (_Float16)v1[1];
    h[6] = (_Float16)v1[2]; h[7] = (_Float16)v1[3];
    *(f16x8*)(dst + i) = h;
}

// 16 MFMA for quadrant (MH,NH) from fragment sets AF,BF (literal idx, rule #20)
#define MFMA16(AF, BF, MH, NH) do {                                          \
    __builtin_amdgcn_s_setprio(1);                                           \
    _Pragma("unroll")                                                        \
    for (int kk = 0; kk < 2; ++kk)                                           \
        _Pragma("unroll")                                                    \
        for (int m = 0; m < 4; ++m)                                          \
            _Pragma("unroll")                                                \
            for (int n = 0; n < 2; ++n)                                      \
                acc[MH][NH][m][n] = __builtin_amdgcn_mfma_f32_16x16x32_f16(  \
                    AF[kk][m], BF[kk][n], acc[MH][NH][m][n], 0, 0, 0);       \
    __builtin_amdgcn_s_setprio(0);                                           \
} while (0)

// ---------------- main GEMM: persistent blocks x R12 window pipeline -------
// Grid = 256 (1 block/CU); each block runs 3 tiles back-to-back. Removes the
// 2 generation boundaries of the 768-block launch: epilogue stores are
// issued WITHOUT drain, next tile's staging loads queue behind them, and the
// peel's WAIT_VM(4) retires stores+A0+B0 in issue order (vmcnt counts both).
// Race audit: prev tail reads parity-1 slots; next prologue (pre-barrier)
// writes parity-0 only; parity-1 staging starts after the peel's first BAR,
// when all waves' prior reads have retired (lgkm precedes barrier arrival).
__launch_bounds__(512, 2)
__global__ void gemm16(const _Float16* __restrict__ A16,
                       const void* __restrict__ cnt,
                       const _Float16* __restrict__ W16,
                       const float* __restrict__ bias,
                       float* __restrict__ Y) {
    __shared__ __align__(16) char Aslot[2][2][128 * ROWB];  // [half][parity]
    __shared__ __align__(16) char Bslot[2][2][128 * ROWB];  // 128 KiB total

    // T1: bijective XCD-aware swizzle on the 256-block grid (256 % 8 == 0)
    const int bid0 = blockIdx.x;
    const int sbid = (bid0 & 7) * 32 + (bid0 >> 3);

    const int tid = threadIdx.x;
    const int l = tid & 63;
    const int w = tid >> 6;   // wave 0..7
    const int wr = w >> 2;    // 0..1 : 64-row strip within each A-half
    const int wc = w & 3;     // 0..3 : 32-col strip within each B-half
    const int lr = l & 15;
    const int lk = l >> 4;

    // Staging: half-tile = 128 rows x 64 K f16 = 16 KiB = 2 gl16/thread.
    // Wave w covers rows [w*16, w*16+16). Source pre-swizzled (rule #21):
    // lane l -> row w*16+8i+(l>>3), byte ((l&7)*16)^((l>>3)<<4).
    const int laneoff = ((l & 7) * 16) ^ ((l >> 3) << 4);
    const size_t srcoff = (size_t)(w * 16 + (l >> 3)) * (KD * 2) + laneoff;

    #pragma unroll 1
    for (int g = 0; g < NGEN; ++g) {
        const int wgid = g * 256 + sbid;
        const int mt = wgid / (ND / BN);
        const int nt = wgid % (ND / BN);
        const int row0 = mt * BM;
        const int col0 = nt * BN;

        const int e = find_expert(cnt, row0);
        const _Float16* We = W16 + (size_t)e * ND * KD;

        const char* gA0 = (const char*)A16 + (size_t)row0 * (KD * 2);
        const char* gA1 = gA0 + (size_t)128 * (KD * 2);
        const char* gB0 = (const char*)We + (size_t)col0 * (KD * 2);
        const char* gB1 = gB0 + (size_t)128 * (KD * 2);

        auto stage_half = [&](const char* ghalf, char* slot, int t) {
            const char* s = ghalf + t * 128 + srcoff;
            gl16(s,                slot + w * 2048);
            gl16(s + 8 * (KD * 2), slot + w * 2048 + 1024);
        };

        f32x4 acc[2][2][4][2] = {};   // [mh][nh][m][n] -> AGPR side
        f16x8 af0[2][4], af1[2][4], bf0[2][2], bf1[2][2];

        auto read_A = [&](f16x8 (&af)[2][4], const char* slot) {
            #pragma unroll
            for (int kk = 0; kk < 2; ++kk)
                #pragma unroll
                for (int m = 0; m < 4; ++m) {
                    int r = wr * 64 + m * 16 + lr;
                    af[kk][m] = *(const f16x8*)&slot[swz(r, kk * 64 + lk * 16)];
                }
        };
        auto read_B = [&](f16x8 (&bf)[2][2], const char* slot) {
            #pragma unroll
            for (int kk = 0; kk < 2; ++kk)
                #pragma unroll
                for (int n = 0; n < 2; ++n) {
                    int r = wc * 32 + n * 16 + lr;
                    bf[kk][n] = *(const f16x8*)&slot[swz(r, kk * 64 + lk * 16)];
                }
        };

        // Prologue: tile 0's 4 half-tiles into parity-0 (disjoint from the
        // previous tile's tail, which reads parity-1 only).
        stage_half(gA0, &Aslot[0][0][0], 0);
        stage_half(gB0, &Bslot[0][0][0], 0);
        stage_half(gA1, &Aslot[1][0][0], 0);
        stage_half(gB1, &Bslot[1][0][0], 0);

        // ---- t=0 peel ----
        // Queue here (g>0): [4 bias loads + 64 C-stores][A0 2][B0 2][A1 2][B1 2].
        // WAIT_VM(4) retires everything except A1,B1 -- stores drain under the
        // staging latency instead of at an exposed boundary.
        WAIT_VM(4);
        BAR();
        read_A(af0, Aslot[0][0]);
        read_B(bf0, Bslot[0][0]);
        stage_half(gA0, &Aslot[0][1][0], 1);
        WAIT_VM(4);                       // A1(0) done
        BAR();
        read_A(af1, Aslot[1][0]);
        stage_half(gB0, &Bslot[0][1][0], 1);
        MFMA16(af0, bf0, 0, 0);
        WAIT_VM(4);                       // B1(0) done
        BAR();
        read_B(bf1, Bslot[1][0]);
        stage_half(gA1, &Aslot[1][1][0], 1);
        MFMA16(af1, bf0, 1, 0);
        stage_half(gB1, &Bslot[1][1][0], 1);
        MFMA16(af0, bf1, 0, 1);

        // ---- main loop t=1..14: 3 windows, read-ahead-one-quadrant ----
        for (int t = 1; t < NSTEP - 1; ++t) {
            const int par = t & 1, nxt = par ^ 1;
            // w0: needs A0,B0(t). MFMA Q11 of tile t-1.
            WAIT_VM(4);
            BAR();
            read_A(af0, Aslot[0][par]);
            read_B(bf0, Bslot[0][par]);
            stage_half(gA0, &Aslot[0][nxt][0], t + 1);
            MFMA16(af1, bf1, 1, 1);
            // w1: needs A1(t). MFMA Q00(t).
            WAIT_VM(4);
            BAR();
            read_A(af1, Aslot[1][par]);
            stage_half(gB0, &Bslot[0][nxt][0], t + 1);
            MFMA16(af0, bf0, 0, 0);
            // w2 (merged): needs B1(t). MFMA Q10(t), then Q01(t).
            WAIT_VM(4);
            BAR();
            read_B(bf1, Bslot[1][par]);
            stage_half(gA1, &Aslot[1][nxt][0], t + 1);
            MFMA16(af1, bf0, 1, 0);
            stage_half(gB1, &Bslot[1][nxt][0], t + 1);
            MFMA16(af0, bf1, 0, 1);
        }

        // ---- t=15 tail: drain 4 -> 2 -> 0 (reads parity-1 slots only) ----
        {
            const int par = (NSTEP - 1) & 1;
            WAIT_VM(4);                   // A0,B0(15) done
            BAR();
            read_A(af0, Aslot[0][par]);
            read_B(bf0, Bslot[0][par]);
            MFMA16(af1, bf1, 1, 1);       // Q11(14)
            WAIT_VM(2);                   // A1(15) done
            BAR();
            read_A(af1, Aslot[1][par]);
            MFMA16(af0, bf0, 0, 0);
            WAIT_VM(0);                   // B1(15) done
            BAR();
            read_B(bf1, Bslot[1][par]);
            MFMA16(af1, bf0, 1, 0);
            MFMA16(af0, bf1, 0, 1);
            MFMA16(af1, bf1, 1, 1);
        }

        // Epilogue: 16x16 C/D layout col = lane&15, row = (lane>>4)*4 + j.
        // Stores are issued and NOT drained -- they retire under the next
        // tile's prologue (WAIT_VM counts them ahead of the staging loads).
        float bv[2][2];
        #pragma unroll
        for (int nh = 0; nh < 2; ++nh)
            #pragma unroll
            for (int n = 0; n < 2; ++n)
                bv[nh][n] = bias[(size_t)e * ND + col0 + nh * 128 + wc * 32 + n * 16 + lr];
        #pragma unroll
        for (int mh = 0; mh < 2; ++mh)
            #pragma unroll
            for (int nh = 0; nh < 2; ++nh)
                #pragma unroll
                for (int m = 0; m < 4; ++m)
                    #pragma unroll
                    for (int j = 0; j < 4; ++j) {
                        int r = row0 + mh * 128 + wr * 64 + m * 16 + lk * 4 + j;
                        float* yp = Y + (size_t)r * ND + col0 + nh * 128 + wc * 32 + lr;
                        yp[0]  = acc[mh][nh][m][0][j] + bv[nh][0];
                        yp[16] = acc[mh][nh][m][1][j] + bv[nh][1];
                    }
    }
}

// ---------------- fallback (R3-class 256^2 reg-staging, known-good) -------
__launch_bounds__(512, 2)
__global__ void fallback_gemm(const float* __restrict__ A,
                              const void* __restrict__ cnt,
                              const float* __restrict__ W,
                              const float* __restrict__ bias,
                              float* __restrict__ Y) {
    __shared__ __align__(16) char ldsbuf[2][2][BM * ROWB];

    const int nwg = gridDim.x;
    const int bid0 = blockIdx.x;
    const int wgid = (bid0 & 7) * (nwg >> 3) + (bid0 >> 3);

    const int mt = wgid / (ND / BN);
    const int nt = wgid % (ND / BN);
    const int row0 = mt * BM;
    const int col0 = nt * BN;

    const int e = find_expert(cnt, row0);
    const float* We = W + (size_t)e * ND * KD;

    const int tid = threadIdx.x;
    const int lane = tid & 63;
    const int w = tid >> 6;
    const int wr = w >> 2;
    const int wc = w & 3;
    const int lr = lane & 15;
    const int lk = lane >> 4;

    int soff[4];
    size_t aoff[4], boff[4];
    #pragma unroll
    for (int c = 0; c < 4; ++c) {
        int q = c * 512 + tid;
        int r = q >> 3;
        int kb = (q & 7) * 8;
        soff[c] = swz(r, kb * 2);
        aoff[c] = (size_t)(row0 + r) * KD + kb;
        boff[c] = (size_t)(col0 + r) * KD + kb;
    }

    f32x4 ra[4][2], rb[4][2];

    auto load_regs = [&](int ks) {
        const int k0 = ks * BK;
        #pragma unroll
        for (int c = 0; c < 4; ++c) {
            const float* ap = A + aoff[c] + k0;
            ra[c][0] = *(const f32x4*)ap;
            ra[c][1] = *(const f32x4*)(ap + 4);
            const float* bp = We + boff[c] + k0;
            rb[c][0] = *(const f32x4*)bp;
            rb[c][1] = *(const f32x4*)(bp + 4);
        }
    };

    auto write_lds = [&](int buf) {
        #pragma unroll
        for (int c = 0; c < 4; ++c) {
            union { f16x8 v; fp16x2 h[4]; } ua, ub;
            ua.h[0] = __builtin_amdgcn_cvt_pkrtz(ra[c][0][0], ra[c][0][1]);
            ua.h[1] = __builtin_amdgcn_cvt_pkrtz(ra[c][0][2], ra[c][0][3]);
            ua.h[2] = __builtin_amdgcn_cvt_pkrtz(ra[c][1][0], ra[c][1][1]);
            ua.h[3] = __builtin_amdgcn_cvt_pkrtz(ra[c][1][2], ra[c][1][3]);
            ub.h[0] = __builtin_amdgcn_cvt_pkrtz(rb[c][0][0], rb[c][0][1]);
            ub.h[1] = __builtin_amdgcn_cvt_pkrtz(rb[c][0][2], rb[c][0][3]);
            ub.h[2] = __builtin_amdgcn_cvt_pkrtz(rb[c][1][0], rb[c][1][1]);
            ub.h[3] = __builtin_amdgcn_cvt_pkrtz(rb[c][1][2], rb[c][1][3]);
            *(f16x8*)&ldsbuf[buf][0][soff[c]] = ua.v;
            *(f16x8*)&ldsbuf[buf][1][soff[c]] = ub.v;
        }
    };

    f32x4 acc[8][4] = {};

    auto compute = [&](const char* Asb, const char* Bsb) {
        #pragma unroll
        for (int kk = 0; kk < 2; ++kk) {
            f16x8 af[8], bf[4];
            #pragma unroll
            for (int m = 0; m < 8; ++m) {
                int r = wr * 128 + m * 16 + lr;
                af[m] = *(const f16x8*)&Asb[swz(r, kk * 64 + lk * 16)];
            }
            #pragma unroll
            for (int n = 0; n < 4; ++n) {
                int r = wc * 64 + n * 16 + lr;
                bf[n] = *(const f16x8*)&Bsb[swz(r, kk * 64 + lk * 16)];
            }
            #pragma unroll
            for (int m = 0; m < 8; ++m)
                #pragma unroll
                for (int n = 0; n < 4; ++n)
                    acc[m][n] = __builtin_amdgcn_mfma_f32_16x16x32_f16(
                        af[m], bf[n], acc[m][n], 0, 0, 0);
        }
    };

    load_regs(0);
    write_lds(0);
    __syncthreads();

    for (int t = 0; t < NSTEP; ++t) {
        const int buf = t & 1;
        if (t + 1 < NSTEP) load_regs(t + 1);
        compute(ldsbuf[buf][0], ldsbuf[buf][1]);
        __syncthreads();
        if (t + 1 < NSTEP) write_lds(buf ^ 1);
        __syncthreads();
    }

    const int cb = col0 + wc * 64;
    const int rb0_ = row0 + wr * 128;
    float bv[4];
    #pragma unroll
    for (int n = 0; n < 4; ++n) bv[n] = bias[(size_t)e * ND + cb + n * 16 + lr];
    #pragma unroll
    for (int m = 0; m < 8; ++m) {
        #pragma unroll
        for (int j = 0; j < 4; ++j) {
            int r = rb0_ + m * 16 + lk * 4 + j;
            float* yp = Y + (size_t)r * ND + cb + lr;
            #pragma unroll
            for (int n = 0; n < 4; ++n)
                yp[n * 16] = acc[m][n][j] + bv[n];
        }
    }
}

extern "C" void kernel_launch(void* const* d_in, const int* in_sizes, int n_in,
                              void* d_out, int out_size, void* d_ws, size_t ws_size,
                              hipStream_t stream) {
    const float* inp  = (const float*)d_in[0];
    const void*  cnt  = d_in[1];               // int32 or int64, detected in-kernel
    const float* wgt  = (const float*)d_in[2];
    const float* bias = (const float*)d_in[3];
    float* out = (float*)d_out;

    if (ws_size >= NEED_WS) {
        _Float16* ws16 = (_Float16*)d_ws;
        cvt_kernel<<<dim3((ASZ + WSZ) / (8 * 256)), dim3(256), 0, stream>>>(inp, wgt, ws16);
        gemm16<<<dim3(256), dim3(512), 0, stream>>>(ws16, cnt, ws16 + ASZ, bias, out);
    } else {
        dim3 grid((TT / BM) * (ND / BN));      // 64 * 12 = 768 blocks
        fallback_gemm<<<grid, dim3(512), 0, stream>>>(inp, cnt, wgt, bias, out);
    }
}

// Round 16
// 194.060 us; speedup vs baseline: 1.1680x; 1.1680x over previous
//
#include <hip/hip_runtime.h>

typedef __attribute__((ext_vector_type(8)))  _Float16 f16x8;
typedef __attribute__((ext_vector_type(2)))  __fp16   fp16x2;  // cvt_pkrtz return type
typedef __attribute__((ext_vector_type(4)))  float    f32x4;

#define TT 16384
#define KD 1024
#define ND 3072
#define NE 16
#define ASZ (TT * KD)                   // 16777216 elements
#define WSZ (NE * ND * KD)              // 50331648 elements
#define NEED_WS ((size_t)(ASZ + WSZ) * 2)

#define BM 256
#define BN 256
#define BK 64
#define NSTEP (KD / BK)                 // 16
#define ROWB (BK * 2)                   // 128 B per LDS row (f16)

#define BAR() __builtin_amdgcn_s_barrier()
#define WAIT_VM(n) asm volatile("s_waitcnt vmcnt(" #n ")" ::: "memory")

// XOR swizzle: conflict-free ds_read_b128 column access on 128B rows (m201).
__device__ __forceinline__ int swz(int row, int kbyte) {
    return row * ROWB + (kbyte ^ ((row & 7) << 4));
}

__device__ __forceinline__ int find_expert(const void* cntp, int row0) {
    // JAX default config demotes int64 -> int32; detect which layout we got.
    const int* w = (const int*)cntp;
    int oddsum = 0;
    #pragma unroll
    for (int i = 1; i < 16; i += 2) oddsum |= w[i];
    int e = 0;
    long long cum = 0;
    if (oddsum == 0) {  // int64 counts
        const long long* c = (const long long*)cntp;
        #pragma unroll
        for (int i = 0; i < NE; ++i) { if ((long long)row0 >= cum) e = i; cum += c[i]; }
    } else {            // int32 counts
        #pragma unroll
        for (int i = 0; i < NE; ++i) { if ((long long)row0 >= cum) e = i; cum += w[i]; }
    }
    return e;
}

// Direct global->LDS DMA, 16B/lane. LDS dest = wave-uniform base + lane*16.
__device__ __forceinline__ void gl16(const void* g, void* l) {
    __builtin_amdgcn_global_load_lds(
        (const __attribute__((address_space(1))) unsigned int*)g,
        (__attribute__((address_space(3))) unsigned int*)l, 16, 0, 0);
}

// ---------------- pre-pass: fp32 -> f16 for A and W ----------------
__global__ __launch_bounds__(256) void cvt_kernel(const float* __restrict__ A,
                                                  const float* __restrict__ W,
                                                  _Float16* __restrict__ dst) {
    size_t i = ((size_t)blockIdx.x * 256 + threadIdx.x) * 8;
    const float* src = (i < (size_t)ASZ) ? (A + i) : (W + (i - ASZ));
    f32x4 v0 = *(const f32x4*)src;
    f32x4 v1 = *(const f32x4*)(src + 4);
    f16x8 h;
    h[0] = (_Float16)v0[0]; h[1] = (_Float16)v0[1];
    h[2] = (_Float16)v0[2]; h[3] = (_Float16)v0[3];
    h[4] = (_Float16)v1[0]; h[5] = (_Float16)v1[1];
    h[6] = (_Float16)v1[2]; h[7] = (_Float16)v1[3];
    *(f16x8*)(dst + i) = h;
}

// 16 MFMA for quadrant (MH,NH) from fragment sets AF,BF (literal idx, rule #20)
#define MFMA16(AF, BF, MH, NH) do {                                          \
    __builtin_amdgcn_s_setprio(1);                                           \
    _Pragma("unroll")                                                        \
    for (int kk = 0; kk < 2; ++kk)                                           \
        _Pragma("unroll")                                                    \
        for (int m = 0; m < 4; ++m)                                          \
            _Pragma("unroll")                                                \
            for (int n = 0; n < 2; ++n)                                      \
                acc[MH][NH][m][n] = __builtin_amdgcn_mfma_f32_16x16x32_f16(  \
                    AF[kk][m], BF[kk][n], acc[MH][NH][m][n], 0, 0, 0);       \
    __builtin_amdgcn_s_setprio(0);                                           \
} while (0)

// ---------------- main GEMM: 3-window read-ahead pipeline (R12, verified) --
// Best verified configuration (133 us, 775 TF, MfmaUtil 34%): slot ring
// A[2][2]/B[2][2] (half x parity); exact counted vmcnt (8->4, 6->4, 6->4 per
// window, never drains mid-loop); each window reads frags for the NEXT
// quadrant while MFMA-ing the CURRENT one; 768 blocks (block turnover hides
// epilogue store drain -- persistent variant measured WORSE, R15).
__launch_bounds__(512, 2)
__global__ void gemm16(const _Float16* __restrict__ A16,
                       const void* __restrict__ cnt,
                       const _Float16* __restrict__ W16,
                       const float* __restrict__ bias,
                       float* __restrict__ Y) {
    __shared__ __align__(16) char Aslot[2][2][128 * ROWB];  // [half][parity]
    __shared__ __align__(16) char Bslot[2][2][128 * ROWB];  // 128 KiB total

    // T1: bijective XCD-aware swizzle (768 % 8 == 0)
    const int nwg = gridDim.x;
    const int bid0 = blockIdx.x;
    const int wgid = (bid0 & 7) * (nwg >> 3) + (bid0 >> 3);

    const int mt = wgid / (ND / BN);
    const int nt = wgid % (ND / BN);
    const int row0 = mt * BM;
    const int col0 = nt * BN;

    const int e = find_expert(cnt, row0);
    const _Float16* We = W16 + (size_t)e * ND * KD;

    const int tid = threadIdx.x;
    const int l = tid & 63;
    const int w = tid >> 6;   // wave 0..7
    const int wr = w >> 2;    // 0..1 : 64-row strip within each A-half
    const int wc = w & 3;     // 0..3 : 32-col strip within each B-half
    const int lr = l & 15;
    const int lk = l >> 4;

    // Staging: half-tile = 128 rows x 64 K f16 = 16 KiB = 2 gl16/thread.
    // Wave w covers rows [w*16, w*16+16). Source pre-swizzled (rule #21):
    // lane l -> row w*16+8i+(l>>3), byte ((l&7)*16)^((l>>3)<<4).
    const int laneoff = ((l & 7) * 16) ^ ((l >> 3) << 4);
    const size_t srcoff = (size_t)(w * 16 + (l >> 3)) * (KD * 2) + laneoff;

    const char* gA0 = (const char*)A16 + (size_t)row0 * (KD * 2);
    const char* gA1 = gA0 + (size_t)128 * (KD * 2);
    const char* gB0 = (const char*)We + (size_t)col0 * (KD * 2);
    const char* gB1 = gB0 + (size_t)128 * (KD * 2);

    auto stage_half = [&](const char* ghalf, char* slot, int t) {
        const char* s = ghalf + t * 128 + srcoff;
        gl16(s,                slot + w * 2048);
        gl16(s + 8 * (KD * 2), slot + w * 2048 + 1024);
    };

    f32x4 acc[2][2][4][2] = {};   // [mh][nh][m][n] -> AGPR side
    f16x8 af0[2][4], af1[2][4], bf0[2][2], bf1[2][2];

    auto read_A = [&](f16x8 (&af)[2][4], const char* slot) {
        #pragma unroll
        for (int kk = 0; kk < 2; ++kk)
            #pragma unroll
            for (int m = 0; m < 4; ++m) {
                int r = wr * 64 + m * 16 + lr;
                af[kk][m] = *(const f16x8*)&slot[swz(r, kk * 64 + lk * 16)];
            }
    };
    auto read_B = [&](f16x8 (&bf)[2][2], const char* slot) {
        #pragma unroll
        for (int kk = 0; kk < 2; ++kk)
            #pragma unroll
            for (int n = 0; n < 2; ++n) {
                int r = wc * 32 + n * 16 + lr;
                bf[kk][n] = *(const f16x8*)&slot[swz(r, kk * 64 + lk * 16)];
            }
    };

    // Prologue: tile 0's 4 half-tiles, in read-need order (A0,B0,A1,B1).
    stage_half(gA0, &Aslot[0][0][0], 0);
    stage_half(gB0, &Bslot[0][0][0], 0);
    stage_half(gA1, &Aslot[1][0][0], 0);
    stage_half(gB1, &Bslot[1][0][0], 0);

    // ---- t=0 peel (no Q11-of-prev to compute in w0) ----
    WAIT_VM(4);                       // A0,B0(0) done; A1,B1(0) in flight
    BAR();
    read_A(af0, Aslot[0][0]);
    read_B(bf0, Bslot[0][0]);
    stage_half(gA0, &Aslot[0][1][0], 1);
    WAIT_VM(4);                       // A1(0) done
    BAR();
    read_A(af1, Aslot[1][0]);
    stage_half(gB0, &Bslot[0][1][0], 1);
    MFMA16(af0, bf0, 0, 0);
    WAIT_VM(4);                       // B1(0) done
    BAR();
    read_B(bf1, Bslot[1][0]);
    stage_half(gA1, &Aslot[1][1][0], 1);
    MFMA16(af1, bf0, 1, 0);
    stage_half(gB1, &Bslot[1][1][0], 1);
    MFMA16(af0, bf1, 0, 1);

    // ---- main loop t=1..14: 3 windows, read-ahead-one-quadrant ----
    for (int t = 1; t < NSTEP - 1; ++t) {
        const int par = t & 1, nxt = par ^ 1;
        // w0: needs A0,B0(t). MFMA Q11 of tile t-1 (af1,bf1 still loaded).
        WAIT_VM(4);
        BAR();
        read_A(af0, Aslot[0][par]);
        read_B(bf0, Bslot[0][par]);
        stage_half(gA0, &Aslot[0][nxt][0], t + 1);
        MFMA16(af1, bf1, 1, 1);
        // w1: needs A1(t). MFMA Q00(t) (af0,bf0 read a full window ago).
        WAIT_VM(4);
        BAR();
        read_A(af1, Aslot[1][par]);
        stage_half(gB0, &Bslot[0][nxt][0], t + 1);
        MFMA16(af0, bf0, 0, 0);
        // w2 (merged): needs B1(t). MFMA Q10(t), then Q01(t).
        WAIT_VM(4);
        BAR();
        read_B(bf1, Bslot[1][par]);
        stage_half(gA1, &Aslot[1][nxt][0], t + 1);
        MFMA16(af1, bf0, 1, 0);
        stage_half(gB1, &Bslot[1][nxt][0], t + 1);
        MFMA16(af0, bf1, 0, 1);
    }

    // ---- t=15 tail: drain 4 -> 2 -> 0 ----
    {
        const int par = (NSTEP - 1) & 1;
        WAIT_VM(4);                   // A0,B0(15) done
        BAR();
        read_A(af0, Aslot[0][par]);
        read_B(bf0, Bslot[0][par]);
        MFMA16(af1, bf1, 1, 1);       // Q11(14)
        WAIT_VM(2);                   // A1(15) done
        BAR();
        read_A(af1, Aslot[1][par]);
        MFMA16(af0, bf0, 0, 0);
        WAIT_VM(0);                   // B1(15) done
        BAR();
        read_B(bf1, Bslot[1][par]);
        MFMA16(af1, bf0, 1, 0);
        MFMA16(af0, bf1, 0, 1);
        MFMA16(af1, bf1, 1, 1);
    }

    // Epilogue: 16x16 C/D layout col = lane&15, row = (lane>>4)*4 + j
    float bv[2][2];
    #pragma unroll
    for (int nh = 0; nh < 2; ++nh)
        #pragma unroll
        for (int n = 0; n < 2; ++n)
            bv[nh][n] = bias[(size_t)e * ND + col0 + nh * 128 + wc * 32 + n * 16 + lr];
    #pragma unroll
    for (int mh = 0; mh < 2; ++mh)
        #pragma unroll
        for (int nh = 0; nh < 2; ++nh)
            #pragma unroll
            for (int m = 0; m < 4; ++m)
                #pragma unroll
                for (int j = 0; j < 4; ++j) {
                    int r = row0 + mh * 128 + wr * 64 + m * 16 + lk * 4 + j;
                    float* yp = Y + (size_t)r * ND + col0 + nh * 128 + wc * 32 + lr;
                    yp[0]  = acc[mh][nh][m][0][j] + bv[nh][0];
                    yp[16] = acc[mh][nh][m][1][j] + bv[nh][1];
                }
}

// ---------------- fallback (R3-class 256^2 reg-staging, known-good) -------
__launch_bounds__(512, 2)
__global__ void fallback_gemm(const float* __restrict__ A,
                              const void* __restrict__ cnt,
                              const float* __restrict__ W,
                              const float* __restrict__ bias,
                              float* __restrict__ Y) {
    __shared__ __align__(16) char ldsbuf[2][2][BM * ROWB];

    const int nwg = gridDim.x;
    const int bid0 = blockIdx.x;
    const int wgid = (bid0 & 7) * (nwg >> 3) + (bid0 >> 3);

    const int mt = wgid / (ND / BN);
    const int nt = wgid % (ND / BN);
    const int row0 = mt * BM;
    const int col0 = nt * BN;

    const int e = find_expert(cnt, row0);
    const float* We = W + (size_t)e * ND * KD;

    const int tid = threadIdx.x;
    const int lane = tid & 63;
    const int w = tid >> 6;
    const int wr = w >> 2;
    const int wc = w & 3;
    const int lr = lane & 15;
    const int lk = lane >> 4;

    int soff[4];
    size_t aoff[4], boff[4];
    #pragma unroll
    for (int c = 0; c < 4; ++c) {
        int q = c * 512 + tid;
        int r = q >> 3;
        int kb = (q & 7) * 8;
        soff[c] = swz(r, kb * 2);
        aoff[c] = (size_t)(row0 + r) * KD + kb;
        boff[c] = (size_t)(col0 + r) * KD + kb;
    }

    f32x4 ra[4][2], rb[4][2];

    auto load_regs = [&](int ks) {
        const int k0 = ks * BK;
        #pragma unroll
        for (int c = 0; c < 4; ++c) {
            const float* ap = A + aoff[c] + k0;
            ra[c][0] = *(const f32x4*)ap;
            ra[c][1] = *(const f32x4*)(ap + 4);
            const float* bp = We + boff[c] + k0;
            rb[c][0] = *(const f32x4*)bp;
            rb[c][1] = *(const f32x4*)(bp + 4);
        }
    };

    auto write_lds = [&](int buf) {
        #pragma unroll
        for (int c = 0; c < 4; ++c) {
            union { f16x8 v; fp16x2 h[4]; } ua, ub;
            ua.h[0] = __builtin_amdgcn_cvt_pkrtz(ra[c][0][0], ra[c][0][1]);
            ua.h[1] = __builtin_amdgcn_cvt_pkrtz(ra[c][0][2], ra[c][0][3]);
            ua.h[2] = __builtin_amdgcn_cvt_pkrtz(ra[c][1][0], ra[c][1][1]);
            ua.h[3] = __builtin_amdgcn_cvt_pkrtz(ra[c][1][2], ra[c][1][3]);
            ub.h[0] = __builtin_amdgcn_cvt_pkrtz(rb[c][0][0], rb[c][0][1]);
            ub.h[1] = __builtin_amdgcn_cvt_pkrtz(rb[c][0][2], rb[c][0][3]);
            ub.h[2] = __builtin_amdgcn_cvt_pkrtz(rb[c][1][0], rb[c][1][1]);
            ub.h[3] = __builtin_amdgcn_cvt_pkrtz(rb[c][1][2], rb[c][1][3]);
            *(f16x8*)&ldsbuf[buf][0][soff[c]] = ua.v;
            *(f16x8*)&ldsbuf[buf][1][soff[c]] = ub.v;
        }
    };

    f32x4 acc[8][4] = {};

    auto compute = [&](const char* Asb, const char* Bsb) {
        #pragma unroll
        for (int kk = 0; kk < 2; ++kk) {
            f16x8 af[8], bf[4];
            #pragma unroll
            for (int m = 0; m < 8; ++m) {
                int r = wr * 128 + m * 16 + lr;
                af[m] = *(const f16x8*)&Asb[swz(r, kk * 64 + lk * 16)];
            }
            #pragma unroll
            for (int n = 0; n < 4; ++n) {
                int r = wc * 64 + n * 16 + lr;
                bf[n] = *(const f16x8*)&Bsb[swz(r, kk * 64 + lk * 16)];
            }
            #pragma unroll
            for (int m = 0; m < 8; ++m)
                #pragma unroll
                for (int n = 0; n < 4; ++n)
                    acc[m][n] = __builtin_amdgcn_mfma_f32_16x16x32_f16(
                        af[m], bf[n], acc[m][n], 0, 0, 0);
        }
    };

    load_regs(0);
    write_lds(0);
    __syncthreads();

    for (int t = 0; t < NSTEP; ++t) {
        const int buf = t & 1;
        if (t + 1 < NSTEP) load_regs(t + 1);
        compute(ldsbuf[buf][0], ldsbuf[buf][1]);
        __syncthreads();
        if (t + 1 < NSTEP) write_lds(buf ^ 1);
        __syncthreads();
    }

    const int cb = col0 + wc * 64;
    const int rb0_ = row0 + wr * 128;
    float bv[4];
    #pragma unroll
    for (int n = 0; n < 4; ++n) bv[n] = bias[(size_t)e * ND + cb + n * 16 + lr];
    #pragma unroll
    for (int m = 0; m < 8; ++m) {
        #pragma unroll
        for (int j = 0; j < 4; ++j) {
            int r = rb0_ + m * 16 + lk * 4 + j;
            float* yp = Y + (size_t)r * ND + cb + lr;
            #pragma unroll
            for (int n = 0; n < 4; ++n)
                yp[n * 16] = acc[m][n][j] + bv[n];
        }
    }
}

extern "C" void kernel_launch(void* const* d_in, const int* in_sizes, int n_in,
                              void* d_out, int out_size, void* d_ws, size_t ws_size,
                              hipStream_t stream) {
    const float* inp  = (const float*)d_in[0];
    const void*  cnt  = d_in[1];               // int32 or int64, detected in-kernel
    const float* wgt  = (const float*)d_in[2];
    const float* bias = (const float*)d_in[3];
    float* out = (float*)d_out;

    dim3 grid((TT / BM) * (ND / BN));          // 64 * 12 = 768 blocks
    dim3 block(512);

    if (ws_size >= NEED_WS) {
        _Float16* ws16 = (_Float16*)d_ws;
        cvt_kernel<<<dim3((ASZ + WSZ) / (8 * 256)), dim3(256), 0, stream>>>(inp, wgt, ws16);
        gemm16<<<grid, block, 0, stream>>>(ws16, cnt, ws16 + ASZ, bias, out);
    } else {
        fallback_gemm<<<grid, block, 0, stream>>>(inp, cnt, wgt, bias, out);
    }
}